// Round 17
// baseline (187.154 us; speedup 1.0000x reference)
//
#include <hip/hip_runtime.h>
#include <hip/hip_bf16.h>
#include <math.h>

#define NB      2048
#define N_NUC   4
#define N_ELEC  16
#define N_PART  20
#define N_NODES (NB * N_PART)     // 40960
#define NE      307200
#define DD      64
#define KK      128
#define EMB     256
#define N_ESLOT (NB * N_ELEC)     // 32768
#define NKEY    (N_ESLOT * 3)     // 98304
#define NSB     96                // scan blocks (NKEY/1024)
#define TRS     76                // LDS transpose row stride (ushorts)
#define ZLS     392               // zgout LDS row stride (ushorts, padded)

typedef __attribute__((ext_vector_type(8))) short bf16x8;
typedef __attribute__((ext_vector_type(4))) float f32x4;
typedef unsigned short ushort_t;

__device__ __forceinline__ unsigned short f2b(float f) {   // RTNE (prep only)
    union { float f; unsigned int u; } v; v.f = f;
    unsigned int r = (v.u + 0x7fffu + ((v.u >> 16) & 1u)) >> 16;
    return (unsigned short)r;
}
__device__ __forceinline__ unsigned short f2b_hup(float f) { // round-half-up (cheap)
    union { float f; unsigned int u; } v; v.f = f;
    return (unsigned short)((v.u + 0x8000u) >> 16);
}
__device__ __forceinline__ float b2f(unsigned short u) {
    union { unsigned int u; float f; } v; v.u = ((unsigned int)u) << 16;
    return v.f;
}
__device__ __forceinline__ float fexp2(float x) {
    float r; asm("v_exp_f32 %0, %1" : "=v"(r) : "v"(x)); return r;
}
__device__ __forceinline__ float flog2(float x) {
    float r; asm("v_log_f32 %0, %1" : "=v"(r) : "v"(x)); return r;
}
// softplus(x) - ln2 = max(x,0) + ln2*(log2(1+2^(-|x|*log2e)) - 1)
__device__ __forceinline__ float ssp_fast(float x) {
    float t = fexp2(fabsf(x) * -1.4426950408889634f);
    float l = flog2(1.0f + t);
    return fmaxf(x, 0.0f) + 0.6931471805599453f * (l - 1.0f);
}
__device__ __forceinline__ unsigned int cvtpk(float lo, float hi) {
    unsigned int r;
    asm("v_cvt_pk_bf16_f32 %0, %1, %2" : "=v"(r) : "v"(lo), "v"(hi));
    return r;
}

// ================= setup: zero_cnt ∥ weight-pack ∥ hx_nuc (fused, independent) =================
__global__ __launch_bounds__(256) void setup_kernel(
    const float* __restrict__ nuc,
    const float* __restrict__ w_n_W1, const float* __restrict__ w_same_W1, const float* __restrict__ w_anti_W1,
    const float* __restrict__ w_n_W2, const float* __restrict__ w_same_W2, const float* __restrict__ w_anti_W2,
    const float* __restrict__ h_W,
    const float* __restrict__ g_n_W, const float* __restrict__ g_same_W, const float* __restrict__ g_anti_W,
    const float* __restrict__ w_n_b1, const float* __restrict__ w_same_b1, const float* __restrict__ w_anti_b1,
    const float* __restrict__ w_n_b2, const float* __restrict__ w_same_b2, const float* __restrict__ w_anti_b2,
    const float* __restrict__ g_n_b, const float* __restrict__ g_same_b, const float* __restrict__ g_anti_b,
    ushort_t* __restrict__ pack, float* __restrict__ b1cat, float* __restrict__ b2cat,
    float* __restrict__ gbsum, int* __restrict__ cnt, ushort_t* __restrict__ hxb)
{
    int bid = blockIdx.x;
    int tid = threadIdx.x;
    if (bid < 96) {
        int i = bid * 256 + tid;
        int4 z; z.x = 0; z.y = 0; z.z = 0; z.w = 0;
        ((int4*)cnt)[i] = z;
        return;
    }
    if (bid >= 182) {
        // hx_nuc (PERMUTED inner layout: pos(c) = (c&15)*8 + (c>>4))
        int t = (bid - 182) * 256 + tid;          // 0..131071
        int nn = t >> 4;
        int l  = t & 15;
        int node = (nn >> 2) * N_PART + (nn & 3);
        const float* src = nuc + (size_t)nn * KK;
        bf16x8 o;
#pragma unroll
        for (int j = 0; j < 8; ++j) o[j] = (short)f2b(src[l + 16 * j]);
        *(bf16x8*)(hxb + (size_t)node * KK + l * 8) = o;
        return;
    }
    // prep: pack weights into MFMA-fragment layout (bf16)
    int c = (bid - 96) * 256 + tid;
    if (c < 1536) {                       // W1pack: nt 0..11 (n=192), ks 0..1
        int lane = c & 63, ks = (c >> 6) & 1, nt = c >> 7;
        ushort_t* dst = pack + (size_t)c * 8;
#pragma unroll
        for (int j = 0; j < 8; ++j) {
            int k = ks * 32 + ((lane >> 4) << 3) + j;
            int n = nt * 16 + (lane & 15);
            float v = (n < 64) ? w_n_W1[k * 64 + n]
                   : (n < 128) ? w_same_W1[k * 64 + n - 64]
                               : w_anti_W1[k * 64 + n - 128];
            dst[j] = f2b(v);
        }
    } else if (c < 1536 + 3072) {         // W2pack: nt 0..23 (n=384), ks 0..1
        int c2 = c - 1536;
        int lane = c2 & 63, ks = (c2 >> 6) & 1, nt = c2 >> 7;
        ushort_t* dst = pack + (size_t)c * 8;
#pragma unroll
        for (int j = 0; j < 8; ++j) {
            int k = ks * 32 + ((lane >> 4) << 3) + j;
            int n = nt * 16 + (lane & 15);
            float v = (n < 128) ? w_n_W2[k * KK + n]
                   : (n < 256) ? w_same_W2[k * KK + n - 128]
                               : w_anti_W2[k * KK + n - 256];
            dst[j] = f2b(v);
        }
    } else if (c < 1536 + 3072 + 4096) {  // HWT: nt 0..7 (n=128), ks 0..7
        int c3 = c - (1536 + 3072);
        int lane = c3 & 63, ks = (c3 >> 6) & 7, nt = c3 >> 9;
        ushort_t* dst = pack + (size_t)c * 8;
#pragma unroll
        for (int j = 0; j < 8; ++j) {
            int k = ks * 32 + ((lane >> 4) << 3) + j;
            int n = nt * 16 + (lane & 15);
            dst[j] = f2b(h_W[k * KK + n]);
        }
    } else if (c < 20992) {               // GT: nt 0..15 (n=256), ks 0..11 (k=384)
        int c4 = c - (1536 + 3072 + 4096);
        int lane = c4 & 63, ks = (c4 >> 6) % 12, nt = c4 / 768;
        ushort_t* dst = pack + (size_t)c * 8;
#pragma unroll
        for (int j = 0; j < 8; ++j) {
            int k = ks * 32 + ((lane >> 4) << 3) + j;
            int n = nt * 16 + (lane & 15);
            float v = (k < 128) ? g_n_W[k * EMB + n]
                   : (k < 256) ? g_same_W[(k - 128) * EMB + n]
                               : g_anti_W[(k - 256) * EMB + n];
            dst[j] = f2b(v);
        }
    } else if (c < 20992 + 192) {
        int i = c - 20992;
        b1cat[i] = (i < 64) ? w_n_b1[i] : (i < 128) ? w_same_b1[i - 64] : w_anti_b1[i - 128];
    } else if (c < 20992 + 192 + 384) {
        int i = c - 20992 - 192;
        b2cat[i] = (i < 128) ? w_n_b2[i] : (i < 256) ? w_same_b2[i - 128] : w_anti_b2[i - 256];
    } else if (c < 20992 + 192 + 384 + 256) {
        int i = c - 20992 - 192 - 384;
        gbsum[i] = g_n_b[i] + g_same_b[i] + g_anti_b[i];
    }
}

// ================= build: hx_elec MFMA ∥ hist (fused, independent) =================
__global__ __launch_bounds__(256) void build_kernel(
    const float* __restrict__ elec, const ushort_t* __restrict__ HWT,
    const float* __restrict__ h_b, ushort_t* __restrict__ hxb,
    const int* __restrict__ receivers, const int* __restrict__ e_type,
    int* __restrict__ cnt, int* __restrict__ rank)
{
    int bid = blockIdx.x;
    int tid = threadIdx.x;
    if (bid >= 512) {
        // hist
        int e = (bid - 512) * 256 + tid;
        int r = receivers[e];
        int bb = r / N_PART;
        int p = r - bb * N_PART;
        if (p >= N_NUC) {
            int et = e_type[e];
            int t = (et == 1) ? 0 : ((et == 3) ? 1 : 2);
            int key = t * N_ESLOT + (bb * N_ELEC + p - N_NUC);
            rank[e] = atomicAdd(&cnt[key], 1);
        } else {
            rank[e] = -1;
        }
        return;
    }
    // hx_elec rows = elec @ h_W + h_b (MFMA, permuted store)
    int lane = tid & 63;
    int l15 = lane & 15, l4 = lane >> 4;
    int row0 = bid * 64 + (tid >> 6) * 16;

    union { bf16x8 v; unsigned int u[4]; } a[8];
    const float* ep = elec + (size_t)(row0 + l15) * EMB + l4 * 8;
#pragma unroll
    for (int ks = 0; ks < 8; ++ks) {
        f32x4 v0 = *(const f32x4*)(ep + ks * 32);
        f32x4 v1 = *(const f32x4*)(ep + ks * 32 + 4);
        a[ks].u[0] = cvtpk(v0[0], v0[1]); a[ks].u[1] = cvtpk(v0[2], v0[3]);
        a[ks].u[2] = cvtpk(v1[0], v1[1]); a[ks].u[3] = cvtpk(v1[2], v1[3]);
    }

    f32x4 acc[8];
#pragma unroll
    for (int nt = 0; nt < 8; ++nt) acc[nt] = (f32x4)(h_b[nt * 16 + l15]);  // bias in acc
#pragma unroll
    for (int nt = 0; nt < 8; ++nt) {
#pragma unroll
        for (int ks = 0; ks < 8; ++ks) {
            bf16x8 b = *(const bf16x8*)(HWT + ((size_t)(nt * 8 + ks) * 64 + lane) * 8);
            acc[nt] = __builtin_amdgcn_mfma_f32_16x16x32_bf16(a[ks].v, b, acc[nt], 0, 0, 0);
        }
    }
#pragma unroll
    for (int nt = 0; nt < 8; ++nt) {
#pragma unroll
        for (int r = 0; r < 4; ++r) {
            int erow = row0 + l4 * 4 + r;
            int node = (erow >> 4) * N_PART + N_NUC + (erow & 15);
            hxb[(size_t)node * KK + l15 * 8 + nt] = f2b_hup(acc[nt][r]);   // permuted
        }
    }
}

// ---- hierarchical scan: local (96 blocks x 1024 elems) -> bsum (1 tiny); bsum folded at use ----
__global__ __launch_bounds__(256) void scan_local(int* __restrict__ cnt, int* __restrict__ bsum)
{
    __shared__ int sh[256];
    int t = threadIdx.x, bid = blockIdx.x;
    int base = bid * 1024 + t * 4;
    int4 v = *(const int4*)&cnt[base];
    int s = v.x + v.y + v.z + v.w;
    sh[t] = s;
    __syncthreads();
    for (int off = 1; off < 256; off <<= 1) {
        int add = (t >= off) ? sh[t - off] : 0;
        __syncthreads();
        sh[t] += add;
        __syncthreads();
    }
    int pre = sh[t] - s;
    int4 o;
    o.x = pre; o.y = pre + v.x; o.z = o.y + v.y; o.w = o.z + v.z;
    *(int4*)&cnt[base] = o;
    if (t == 255) bsum[bid] = sh[255];
}

__global__ __launch_bounds__(128) void scan_bsum(int* __restrict__ bsum, int* __restrict__ seg,
                                                 int* __restrict__ cnt, int* __restrict__ eidx)
{
    __shared__ int sh[128];
    __shared__ int S1s, C2s, tots;
    int t = threadIdx.x;
    int v = (t < NSB) ? bsum[t] : 0;
    sh[t] = v;
    __syncthreads();
    for (int off = 1; off < 128; off <<= 1) {
        int add = (t >= off) ? sh[t - off] : 0;
        __syncthreads();
        sh[t] += add;
        __syncthreads();
    }
    int pre = sh[t] - v;      // exclusive prefix over block sums
    if (t == 31) S1s = sh[31];
    if (t == 63) C2s = sh[63];
    if (t == NSB - 1) tots = sh[NSB - 1];
    __syncthreads();
    int S1 = S1s, C2 = C2s, tot = tots;
    int pad1 = (16 - (S1 & 15)) & 15;
    int pad2 = (16 - ((C2 + pad1) & 15)) & 15;
    if (t < NSB) {
        int add = ((t >= 32) ? pad1 : 0) + ((t >= 64) ? pad2 : 0);
        bsum[t] = pre + add;
    }
    if (t == NSB) bsum[NSB] = 0;   // zgout reads bsum[96] for the final bucket bound
    // fill ONLY the pad/tail slots of eidx with -1 (replaces 1.2 MB memset)
    if (t < 16) {
        if (t < pad1) eidx[S1 + t] = -1;
    } else if (t < 32) {
        int i = t - 16;
        if (i < pad2) eidx[C2 + pad1 + i] = -1;
    } else if (t < 48) {
        int i = t - 32;
        int T = tot + pad1 + pad2;
        int Tr = (T + 15) & ~15;
        if (T + i < Tr) eidx[T + i] = -1;
    }
    if (t == 0) {
        seg[0] = 0;
        seg[1] = S1 + pad1;
        seg[2] = C2 + pad1 + pad2;
        seg[3] = tot + pad1 + pad2;
        cnt[NKEY] = tot + pad1 + pad2;
    }
}

__global__ __launch_bounds__(256) void scatter_kernel(
    const int* __restrict__ receivers, const int* __restrict__ e_type,
    const int* __restrict__ cnt, const int* __restrict__ bsum,
    const int* __restrict__ rank, int* __restrict__ eidx)
{
    int e = blockIdx.x * 256 + threadIdx.x;
    if (e >= NE) return;
    int rk = rank[e];
    if (rk < 0) return;
    int r = receivers[e];
    int bb = r / N_PART;
    int p = r - bb * N_PART;
    int et = e_type[e];
    int t = (et == 1) ? 0 : ((et == 3) ? 1 : 2);
    int key = t * N_ESLOT + (bb * N_ELEC + p - N_NUC);
    eidx[cnt[key] + bsum[key >> 10] + rk] = e;
}

// ================= fused edge kernel: software-pipelined grid-stride =================
__global__ __launch_bounds__(256, 8) void edge_fused(
    const float* __restrict__ dist, const int* __restrict__ senders,
    const int* __restrict__ eidx, const int* __restrict__ seg,
    const bf16x8* __restrict__ W1p, const float* __restrict__ b1cat,
    const bf16x8* __restrict__ W2p, const float* __restrict__ b2cat,
    const ushort_t* __restrict__ hxb, ushort_t* __restrict__ buf)
{
    __shared__ ushort_t tr[4][16 * TRS];
    int tid = threadIdx.x;
    int wave = tid >> 6, lane = tid & 63;
    int l15 = lane & 15, l4 = lane >> 4;
    int total = seg[3], s1 = seg[1], s2 = seg[2];
    ushort_t* trw = tr[wave];
    int nw = gridDim.x * 4;

    int tile = blockIdx.x * 4 + wave;
    if (tile * 16 >= total) return;

    // prologue: prefetch tile 0 inputs
    int e = eidx[tile * 16 + l15];
    int valid = (e >= 0) ? 1 : 0;
    int ec = valid ? e : 0;
    int snd = senders[ec];
    const float* dp = dist + (size_t)ec * DD + l4 * 8;
    f32x4 v0 = __builtin_nontemporal_load((const f32x4*)(dp));
    f32x4 v1 = __builtin_nontemporal_load((const f32x4*)(dp + 4));
    f32x4 v2 = __builtin_nontemporal_load((const f32x4*)(dp + 32));
    f32x4 v3 = __builtin_nontemporal_load((const f32x4*)(dp + 36));

    while (true) {
        // (1) issue hx[sender] gathers for the CURRENT tile up front — they cover the MFMA chain
        bf16x8 hv[4];
        int vr[4];
#pragma unroll
        for (int r = 0; r < 4; ++r) {
            int m = l4 * 4 + r;
            int sdr = __shfl(snd, m);
            vr[r] = __shfl(valid, m);
            hv[r] = *(const bf16x8*)(hxb + (size_t)sdr * KK + l15 * 8);
        }

        // (2) convert current A-frags (frees v0..v3 for the next prefetch)
        union { bf16x8 v; unsigned int u[4]; } A0, A1;
        A0.u[0] = cvtpk(v0[0], v0[1]); A0.u[1] = cvtpk(v0[2], v0[3]);
        A0.u[2] = cvtpk(v1[0], v1[1]); A0.u[3] = cvtpk(v1[2], v1[3]);
        A1.u[0] = cvtpk(v2[0], v2[1]); A1.u[1] = cvtpk(v2[2], v2[3]);
        A1.u[2] = cvtpk(v3[0], v3[1]); A1.u[3] = cvtpk(v3[2], v3[3]);

        // (3) prefetch NEXT tile's inputs — latency hides under MFMAs below
        int ntile = tile + nw;
        int more = (ntile * 16 < total) ? 1 : 0;
        int valid_n = 0, snd_n = 0;
        if (more) {
            int e_n = eidx[ntile * 16 + l15];
            valid_n = (e_n >= 0) ? 1 : 0;
            int ecn = valid_n ? e_n : 0;
            snd_n = senders[ecn];
            const float* dpn = dist + (size_t)ecn * DD + l4 * 8;
            v0 = __builtin_nontemporal_load((const f32x4*)(dpn));
            v1 = __builtin_nontemporal_load((const f32x4*)(dpn + 4));
            v2 = __builtin_nontemporal_load((const f32x4*)(dpn + 32));
            v3 = __builtin_nontemporal_load((const f32x4*)(dpn + 36));
        }

        int t = (tile * 16 >= s1) + (tile * 16 >= s2);

        // (4) h1 = ssp(dist @ W1[t] + b1[t])  (8 MFMA, bias in acc)
        f32x4 ah[4];
#pragma unroll
        for (int q = 0; q < 4; ++q) ah[q] = (f32x4)(b1cat[t * 64 + q * 16 + l15]);
        const bf16x8* W1b = W1p + (size_t)(t * 4) * 2 * 64;
#pragma unroll
        for (int q = 0; q < 4; ++q) {
            bf16x8 b0 = W1b[(q * 2 + 0) * 64 + lane];
            bf16x8 b1v = W1b[(q * 2 + 1) * 64 + lane];
            ah[q] = __builtin_amdgcn_mfma_f32_16x16x32_bf16(A0.v, b0, ah[q], 0, 0, 0);
            ah[q] = __builtin_amdgcn_mfma_f32_16x16x32_bf16(A1.v, b1v, ah[q], 0, 0, 0);
        }

        // ssp + per-wave LDS transpose (C-frag -> A-frag)
#pragma unroll
        for (int q = 0; q < 4; ++q) {
#pragma unroll
            for (int r = 0; r < 4; ++r) {
                trw[(l4 * 4 + r) * TRS + q * 16 + l15] = f2b_hup(ssp_fast(ah[q][r]));
            }
        }
        bf16x8 a2_0 = *(const bf16x8*)&trw[l15 * TRS + l4 * 8];
        bf16x8 a2_1 = *(const bf16x8*)&trw[l15 * TRS + 32 + l4 * 8];

        // (5) weh = h1 @ W2[t] + b2[t]  (16 MFMA, bias in acc)
        f32x4 aw[8];
#pragma unroll
        for (int n = 0; n < 8; ++n) aw[n] = (f32x4)(b2cat[t * KK + n * 16 + l15]);
        const bf16x8* W2b = W2p + (size_t)(t * 8) * 2 * 64;
#pragma unroll
        for (int n = 0; n < 8; ++n) {
            bf16x8 b0 = W2b[(n * 2 + 0) * 64 + lane];
            bf16x8 b1v = W2b[(n * 2 + 1) * 64 + lane];
            aw[n] = __builtin_amdgcn_mfma_f32_16x16x32_bf16(a2_0, b0, aw[n], 0, 0, 0);
            aw[n] = __builtin_amdgcn_mfma_f32_16x16x32_bf16(a2_1, b1v, aw[n], 0, 0, 0);
        }

        // (6) epilogue: * hx (already in regs), packed cvt, cached store (zgout reads it from L3)
#pragma unroll
        for (int r = 0; r < 4; ++r) {
            float p0 = aw[0][r] * b2f((unsigned short)hv[r][0]);
            float p1 = aw[1][r] * b2f((unsigned short)hv[r][1]);
            float p2 = aw[2][r] * b2f((unsigned short)hv[r][2]);
            float p3 = aw[3][r] * b2f((unsigned short)hv[r][3]);
            float p4 = aw[4][r] * b2f((unsigned short)hv[r][4]);
            float p5 = aw[5][r] * b2f((unsigned short)hv[r][5]);
            float p6 = aw[6][r] * b2f((unsigned short)hv[r][6]);
            float p7 = aw[7][r] * b2f((unsigned short)hv[r][7]);
            union { bf16x8 v; unsigned int u[4]; } O;
            O.u[0] = vr[r] ? cvtpk(p0, p1) : 0u;
            O.u[1] = vr[r] ? cvtpk(p2, p3) : 0u;
            O.u[2] = vr[r] ? cvtpk(p4, p5) : 0u;
            O.u[3] = vr[r] ? cvtpk(p6, p7) : 0u;
            *(bf16x8*)(buf + (size_t)(tile * 16 + l4 * 4 + r) * KK + l15 * 8) = O.v;
        }

        if (!more) break;
        tile = ntile;
        valid = valid_n;
        snd = snd_n;
    }
}

// ================= zgout: fused zgather (→LDS) + gout MFMA, 32 slots/block =================
__global__ __launch_bounds__(512, 4) void zgout_fused(
    const int* __restrict__ cnt, const int* __restrict__ bsum,
    const ushort_t* __restrict__ buf,
    const float* __restrict__ elec, const ushort_t* __restrict__ GT,
    const float* __restrict__ gbsum, float* __restrict__ out)
{
    __shared__ ushort_t zl[32 * ZLS];   // 25,088 B
    __shared__ int bnd[3][33];
    int tid = threadIdx.x;
    int lane = tid & 63;
    int wave = tid >> 6;
    int l15 = lane & 15, l4 = lane >> 4;
    int s0 = blockIdx.x * 32;

    // ---- bounds preload (96 buckets + 3 segment ends) ----
    if (tid < 99) {
        int tt = tid / 33;
        int sl = tid - tt * 33;
        int idx = tt * N_ESLOT + s0 + sl;
        bnd[tt][sl] = cnt[idx] + bsum[idx >> 10];
    }
    __syncthreads();

    // ---- phase 1: bucket sums -> LDS (2 rows per uint2 load) ----
    for (int b = wave; b < 96; b += 8) {
        int sl = b & 31;
        int t  = b >> 5;
        int lo = bnd[t][sl];
        int hi = bnd[t][sl + 1];
        float a0 = 0.0f, a1 = 0.0f, a2 = 0.0f, a3 = 0.0f;
        int i = lo;
        for (; i + 2 <= hi; i += 2) {
            // lanes 0..31 read row i, lanes 32..63 read row i+1 (512B total)
            uint2 v = *(const uint2*)(buf + (size_t)i * KK + 4 * lane);
            a0 += b2f((unsigned short)(v.x & 0xffff));
            a1 += b2f((unsigned short)(v.x >> 16));
            a2 += b2f((unsigned short)(v.y & 0xffff));
            a3 += b2f((unsigned short)(v.y >> 16));
        }
        if (i < hi) {
            uint2 v; v.x = 0u; v.y = 0u;
            if (lane < 32) v = *(const uint2*)(buf + (size_t)i * KK + 4 * lane);
            a0 += b2f((unsigned short)(v.x & 0xffff));
            a1 += b2f((unsigned short)(v.x >> 16));
            a2 += b2f((unsigned short)(v.y & 0xffff));
            a3 += b2f((unsigned short)(v.y >> 16));
        }
        // fold row-parity halves: lane l += lane l^32
        a0 += __shfl_xor(a0, 32);
        a1 += __shfl_xor(a1, 32);
        a2 += __shfl_xor(a2, 32);
        a3 += __shfl_xor(a3, 32);
        if (lane < 32) {
            int base = sl * ZLS + t * KK;
            int p = 4 * lane;
            zl[base + ((p    ) >> 3) + (((p    ) & 7) * 16)] = f2b_hup(a0);
            zl[base + ((p + 1) >> 3) + (((p + 1) & 7) * 16)] = f2b_hup(a1);
            zl[base + ((p + 2) >> 3) + (((p + 2) & 7) * 16)] = f2b_hup(a2);
            zl[base + ((p + 3) >> 3) + (((p + 3) & 7) * 16)] = f2b_hup(a3);
        }
    }
    __syncthreads();

    // ---- phase 2: out = elec + Z @ GT + gb (MFMA, swapped operands) ----
    // 8 waves = 2 row-waves x 4 col-quarters; wave does 16 rows x 64 cols (4 nt)
    int rw = wave & 1;
    int ch = wave >> 1;
    int row0 = s0 + rw * 16;
    int lrow = rw * 16 + l15;
    int ntb = ch * 4;

    bf16x8 zb[12];
#pragma unroll
    for (int ks = 0; ks < 12; ++ks)
        zb[ks] = *(const bf16x8*)&zl[lrow * ZLS + ks * 32 + l4 * 8];

    f32x4 acc[4];
#pragma unroll
    for (int nt = 0; nt < 4; ++nt) acc[nt] = (f32x4)(0.0f);
#pragma unroll
    for (int nt = 0; nt < 4; ++nt) {
#pragma unroll
        for (int ks = 0; ks < 12; ++ks) {
            bf16x8 g = *(const bf16x8*)(GT + ((size_t)((ntb + nt) * 12 + ks) * 64 + lane) * 8);
            acc[nt] = __builtin_amdgcn_mfma_f32_16x16x32_bf16(g, zb[ks], acc[nt], 0, 0, 0);
        }
    }

#pragma unroll
    for (int nt = 0; nt < 4; ++nt) {
        int n0 = (ntb + nt) * 16 + l4 * 4;
        f32x4 gbv = *(const f32x4*)(gbsum + n0);
        size_t o = (size_t)(row0 + l15) * EMB + n0;
        f32x4 ev = *(const f32x4*)(elec + o);
        f32x4 res;
        res[0] = ev[0] + acc[nt][0] + gbv[0];
        res[1] = ev[1] + acc[nt][1] + gbv[1];
        res[2] = ev[2] + acc[nt][2] + gbv[2];
        res[3] = ev[3] + acc[nt][3] + gbv[3];
        *(f32x4*)(out + o) = res;
    }
}

extern "C" void kernel_launch(void* const* d_in, const int* in_sizes, int n_in,
                              void* d_out, int out_size, void* d_ws, size_t ws_size,
                              hipStream_t stream) {
    const float* nuc       = (const float*)d_in[0];
    const float* elec      = (const float*)d_in[1];
    const float* dist      = (const float*)d_in[2];
    const int*   e_type    = (const int*)d_in[3];
    const int*   senders   = (const int*)d_in[4];
    const int*   receivers = (const int*)d_in[5];
    const float* w_same_W1 = (const float*)d_in[6];
    const float* w_same_b1 = (const float*)d_in[7];
    const float* w_same_W2 = (const float*)d_in[8];
    const float* w_same_b2 = (const float*)d_in[9];
    const float* w_anti_W1 = (const float*)d_in[10];
    const float* w_anti_b1 = (const float*)d_in[11];
    const float* w_anti_W2 = (const float*)d_in[12];
    const float* w_anti_b2 = (const float*)d_in[13];
    const float* w_n_W1    = (const float*)d_in[14];
    const float* w_n_b1    = (const float*)d_in[15];
    const float* w_n_W2    = (const float*)d_in[16];
    const float* w_n_b2    = (const float*)d_in[17];
    const float* h_W       = (const float*)d_in[18];
    const float* h_b       = (const float*)d_in[19];
    const float* g_same_W  = (const float*)d_in[20];
    const float* g_same_b  = (const float*)d_in[21];
    const float* g_anti_W  = (const float*)d_in[22];
    const float* g_anti_b  = (const float*)d_in[23];
    const float* g_n_W     = (const float*)d_in[24];
    const float* g_n_b     = (const float*)d_in[25];

    float* out = (float*)d_out;

    // ---- workspace layout ----
    char* w = (char*)d_ws;
    ushort_t* pack = (ushort_t*)w;                         // 20992*16 = 335,872 B
    size_t off = 20992 * 16;
    float* b1cat = (float*)(w + off);  off += 192 * 4;
    float* b2cat = (float*)(w + off);  off += 384 * 4;
    float* gbsum = (float*)(w + off);  off += 256 * 4;
    int*   seg   = (int*)(w + off);    off += 4 * 4;
    off = (off + 255) & ~(size_t)255;
    int*   bsum  = (int*)(w + off);    off += 128 * 4;
    off = (off + 255) & ~(size_t)255;
    ushort_t* hxb = (ushort_t*)(w + off);  off += (size_t)N_NODES * KK * 2;        // 10.5 MB
    ushort_t* buf = (ushort_t*)(w + off);  off += (size_t)(NE + 64) * KK * 2;      // 78.7 MB
    int* cnt  = (int*)(w + off);  off += (size_t)(NKEY + 1) * 4 + 252; off &= ~(size_t)255;
    int* rank = (int*)(w + off);  off += (size_t)NE * 4;
    int* eidx = (int*)(w + off);  off += (size_t)(NE + 64) * 4;

    const ushort_t* W1pack = pack;
    const ushort_t* W2pack = pack + (size_t)1536 * 8;
    const ushort_t* HWT    = pack + (size_t)(1536 + 3072) * 8;
    const ushort_t* GT     = pack + (size_t)(1536 + 3072 + 4096) * 8;

    // A: zero_cnt (96) | prep (86) | hx_nuc (512)  = 694 blocks
    setup_kernel<<<694, 256, 0, stream>>>(
        nuc,
        w_n_W1, w_same_W1, w_anti_W1, w_n_W2, w_same_W2, w_anti_W2,
        h_W, g_n_W, g_same_W, g_anti_W,
        w_n_b1, w_same_b1, w_anti_b1, w_n_b2, w_same_b2, w_anti_b2,
        g_n_b, g_same_b, g_anti_b,
        (ushort_t*)pack, b1cat, b2cat, gbsum, cnt, hxb);

    // B: hx_elec (512) | hist (1200) = 1712 blocks
    build_kernel<<<1712, 256, 0, stream>>>(
        elec, HWT, h_b, hxb, receivers, e_type, cnt, rank);

    scan_local<<<NSB, 256, 0, stream>>>(cnt, bsum);
    scan_bsum<<<1, 128, 0, stream>>>(bsum, seg, cnt, eidx);
    scatter_kernel<<<NE / 256, 256, 0, stream>>>(receivers, e_type, cnt, bsum, rank, eidx);

    edge_fused<<<2048, 256, 0, stream>>>(dist, senders, eidx, seg,
        (const bf16x8*)W1pack, b1cat, (const bf16x8*)W2pack, b2cat, hxb, buf);

    zgout_fused<<<N_ESLOT / 32, 512, 0, stream>>>(cnt, bsum, buf, elec, GT, gbsum, out);
}

// Round 18
// 114.746 us; speedup vs baseline: 1.6310x; 1.6310x over previous
//
#include <hip/hip_runtime.h>
#include <hip/hip_bf16.h>
#include <math.h>

#define NB      2048
#define N_NUC   4
#define N_ELEC  16
#define N_PART  20
#define N_NODES (NB * N_PART)     // 40960
#define NE      307200
#define DD      64
#define KK      128
#define EMB     256
#define N_ESLOT (NB * N_ELEC)     // 32768
#define NKEY    (N_ESLOT * 3)     // 98304
#define NSB     96                // scan blocks (NKEY/1024)
#define TRS     76                // LDS transpose row stride (ushorts)
#define ZLS     392               // zgout LDS row stride (ushorts, padded)

typedef __attribute__((ext_vector_type(8))) short bf16x8;
typedef __attribute__((ext_vector_type(4))) float f32x4;
typedef unsigned short ushort_t;

__device__ __forceinline__ unsigned short f2b(float f) {   // RTNE (prep only)
    union { float f; unsigned int u; } v; v.f = f;
    unsigned int r = (v.u + 0x7fffu + ((v.u >> 16) & 1u)) >> 16;
    return (unsigned short)r;
}
__device__ __forceinline__ unsigned short f2b_hup(float f) { // round-half-up (cheap)
    union { float f; unsigned int u; } v; v.f = f;
    return (unsigned short)((v.u + 0x8000u) >> 16);
}
__device__ __forceinline__ float b2f(unsigned short u) {
    union { unsigned int u; float f; } v; v.u = ((unsigned int)u) << 16;
    return v.f;
}
__device__ __forceinline__ float fexp2(float x) {
    float r; asm("v_exp_f32 %0, %1" : "=v"(r) : "v"(x)); return r;
}
__device__ __forceinline__ float flog2(float x) {
    float r; asm("v_log_f32 %0, %1" : "=v"(r) : "v"(x)); return r;
}
// softplus(x) - ln2 = max(x,0) + ln2*(log2(1+2^(-|x|*log2e)) - 1)
__device__ __forceinline__ float ssp_fast(float x) {
    float t = fexp2(fabsf(x) * -1.4426950408889634f);
    float l = flog2(1.0f + t);
    return fmaxf(x, 0.0f) + 0.6931471805599453f * (l - 1.0f);
}
__device__ __forceinline__ unsigned int cvtpk(float lo, float hi) {
    unsigned int r;
    asm("v_cvt_pk_bf16_f32 %0, %1, %2" : "=v"(r) : "v"(lo), "v"(hi));
    return r;
}

// ================= setup: zero_cnt ∥ weight-pack ∥ hx_nuc (fused, independent) =================
__global__ __launch_bounds__(256) void setup_kernel(
    const float* __restrict__ nuc,
    const float* __restrict__ w_n_W1, const float* __restrict__ w_same_W1, const float* __restrict__ w_anti_W1,
    const float* __restrict__ w_n_W2, const float* __restrict__ w_same_W2, const float* __restrict__ w_anti_W2,
    const float* __restrict__ h_W,
    const float* __restrict__ g_n_W, const float* __restrict__ g_same_W, const float* __restrict__ g_anti_W,
    const float* __restrict__ w_n_b1, const float* __restrict__ w_same_b1, const float* __restrict__ w_anti_b1,
    const float* __restrict__ w_n_b2, const float* __restrict__ w_same_b2, const float* __restrict__ w_anti_b2,
    const float* __restrict__ g_n_b, const float* __restrict__ g_same_b, const float* __restrict__ g_anti_b,
    ushort_t* __restrict__ pack, float* __restrict__ b1cat, float* __restrict__ b2cat,
    float* __restrict__ gbsum, int* __restrict__ cnt, ushort_t* __restrict__ hxb)
{
    int bid = blockIdx.x;
    int tid = threadIdx.x;
    if (bid < 96) {
        int i = bid * 256 + tid;
        int4 z; z.x = 0; z.y = 0; z.z = 0; z.w = 0;
        ((int4*)cnt)[i] = z;
        return;
    }
    if (bid >= 182) {
        // hx_nuc (PERMUTED inner layout: pos(c) = (c&15)*8 + (c>>4))
        int t = (bid - 182) * 256 + tid;          // 0..131071
        int nn = t >> 4;
        int l  = t & 15;
        int node = (nn >> 2) * N_PART + (nn & 3);
        const float* src = nuc + (size_t)nn * KK;
        bf16x8 o;
#pragma unroll
        for (int j = 0; j < 8; ++j) o[j] = (short)f2b(src[l + 16 * j]);
        *(bf16x8*)(hxb + (size_t)node * KK + l * 8) = o;
        return;
    }
    // prep: pack weights into MFMA-fragment layout (bf16)
    int c = (bid - 96) * 256 + tid;
    if (c < 1536) {                       // W1pack: nt 0..11 (n=192), ks 0..1
        int lane = c & 63, ks = (c >> 6) & 1, nt = c >> 7;
        ushort_t* dst = pack + (size_t)c * 8;
#pragma unroll
        for (int j = 0; j < 8; ++j) {
            int k = ks * 32 + ((lane >> 4) << 3) + j;
            int n = nt * 16 + (lane & 15);
            float v = (n < 64) ? w_n_W1[k * 64 + n]
                   : (n < 128) ? w_same_W1[k * 64 + n - 64]
                               : w_anti_W1[k * 64 + n - 128];
            dst[j] = f2b(v);
        }
    } else if (c < 1536 + 3072) {         // W2pack: nt 0..23 (n=384), ks 0..1
        int c2 = c - 1536;
        int lane = c2 & 63, ks = (c2 >> 6) & 1, nt = c2 >> 7;
        ushort_t* dst = pack + (size_t)c * 8;
#pragma unroll
        for (int j = 0; j < 8; ++j) {
            int k = ks * 32 + ((lane >> 4) << 3) + j;
            int n = nt * 16 + (lane & 15);
            float v = (n < 128) ? w_n_W2[k * KK + n]
                   : (n < 256) ? w_same_W2[k * KK + n - 128]
                               : w_anti_W2[k * KK + n - 256];
            dst[j] = f2b(v);
        }
    } else if (c < 1536 + 3072 + 4096) {  // HWT: nt 0..7 (n=128), ks 0..7
        int c3 = c - (1536 + 3072);
        int lane = c3 & 63, ks = (c3 >> 6) & 7, nt = c3 >> 9;
        ushort_t* dst = pack + (size_t)c * 8;
#pragma unroll
        for (int j = 0; j < 8; ++j) {
            int k = ks * 32 + ((lane >> 4) << 3) + j;
            int n = nt * 16 + (lane & 15);
            dst[j] = f2b(h_W[k * KK + n]);
        }
    } else if (c < 20992) {               // GT: nt 0..15 (n=256), ks 0..11 (k=384)
        int c4 = c - (1536 + 3072 + 4096);
        int lane = c4 & 63, ks = (c4 >> 6) % 12, nt = c4 / 768;
        ushort_t* dst = pack + (size_t)c * 8;
#pragma unroll
        for (int j = 0; j < 8; ++j) {
            int k = ks * 32 + ((lane >> 4) << 3) + j;
            int n = nt * 16 + (lane & 15);
            float v = (k < 128) ? g_n_W[k * EMB + n]
                   : (k < 256) ? g_same_W[(k - 128) * EMB + n]
                               : g_anti_W[(k - 256) * EMB + n];
            dst[j] = f2b(v);
        }
    } else if (c < 20992 + 192) {
        int i = c - 20992;
        b1cat[i] = (i < 64) ? w_n_b1[i] : (i < 128) ? w_same_b1[i - 64] : w_anti_b1[i - 128];
    } else if (c < 20992 + 192 + 384) {
        int i = c - 20992 - 192;
        b2cat[i] = (i < 128) ? w_n_b2[i] : (i < 256) ? w_same_b2[i - 128] : w_anti_b2[i - 256];
    } else if (c < 20992 + 192 + 384 + 256) {
        int i = c - 20992 - 192 - 384;
        gbsum[i] = g_n_b[i] + g_same_b[i] + g_anti_b[i];
    }
}

// ================= build: hx_elec MFMA ∥ hist (fused, independent) =================
__global__ __launch_bounds__(256) void build_kernel(
    const float* __restrict__ elec, const ushort_t* __restrict__ HWT,
    const float* __restrict__ h_b, ushort_t* __restrict__ hxb,
    const int* __restrict__ receivers, const int* __restrict__ e_type,
    int* __restrict__ cnt, int* __restrict__ rank)
{
    int bid = blockIdx.x;
    int tid = threadIdx.x;
    if (bid >= 512) {
        // hist
        int e = (bid - 512) * 256 + tid;
        int r = receivers[e];
        int bb = r / N_PART;
        int p = r - bb * N_PART;
        if (p >= N_NUC) {
            int et = e_type[e];
            int t = (et == 1) ? 0 : ((et == 3) ? 1 : 2);
            int key = t * N_ESLOT + (bb * N_ELEC + p - N_NUC);
            rank[e] = atomicAdd(&cnt[key], 1);
        } else {
            rank[e] = -1;
        }
        return;
    }
    // hx_elec rows = elec @ h_W + h_b (MFMA, permuted store)
    int lane = tid & 63;
    int l15 = lane & 15, l4 = lane >> 4;
    int row0 = bid * 64 + (tid >> 6) * 16;

    union { bf16x8 v; unsigned int u[4]; } a[8];
    const float* ep = elec + (size_t)(row0 + l15) * EMB + l4 * 8;
#pragma unroll
    for (int ks = 0; ks < 8; ++ks) {
        f32x4 v0 = *(const f32x4*)(ep + ks * 32);
        f32x4 v1 = *(const f32x4*)(ep + ks * 32 + 4);
        a[ks].u[0] = cvtpk(v0[0], v0[1]); a[ks].u[1] = cvtpk(v0[2], v0[3]);
        a[ks].u[2] = cvtpk(v1[0], v1[1]); a[ks].u[3] = cvtpk(v1[2], v1[3]);
    }

    f32x4 acc[8];
#pragma unroll
    for (int nt = 0; nt < 8; ++nt) acc[nt] = (f32x4)(h_b[nt * 16 + l15]);  // bias in acc
#pragma unroll
    for (int nt = 0; nt < 8; ++nt) {
#pragma unroll
        for (int ks = 0; ks < 8; ++ks) {
            bf16x8 b = *(const bf16x8*)(HWT + ((size_t)(nt * 8 + ks) * 64 + lane) * 8);
            acc[nt] = __builtin_amdgcn_mfma_f32_16x16x32_bf16(a[ks].v, b, acc[nt], 0, 0, 0);
        }
    }
#pragma unroll
    for (int nt = 0; nt < 8; ++nt) {
#pragma unroll
        for (int r = 0; r < 4; ++r) {
            int erow = row0 + l4 * 4 + r;
            int node = (erow >> 4) * N_PART + N_NUC + (erow & 15);
            hxb[(size_t)node * KK + l15 * 8 + nt] = f2b_hup(acc[nt][r]);   // permuted
        }
    }
}

// ---- hierarchical scan: local (96 blocks x 1024 elems) -> bsum (1 tiny); bsum folded at use ----
__global__ __launch_bounds__(256) void scan_local(int* __restrict__ cnt, int* __restrict__ bsum)
{
    __shared__ int sh[256];
    int t = threadIdx.x, bid = blockIdx.x;
    int base = bid * 1024 + t * 4;
    int4 v = *(const int4*)&cnt[base];
    int s = v.x + v.y + v.z + v.w;
    sh[t] = s;
    __syncthreads();
    for (int off = 1; off < 256; off <<= 1) {
        int add = (t >= off) ? sh[t - off] : 0;
        __syncthreads();
        sh[t] += add;
        __syncthreads();
    }
    int pre = sh[t] - s;
    int4 o;
    o.x = pre; o.y = pre + v.x; o.z = o.y + v.y; o.w = o.z + v.z;
    *(int4*)&cnt[base] = o;
    if (t == 255) bsum[bid] = sh[255];
}

__global__ __launch_bounds__(128) void scan_bsum(int* __restrict__ bsum, int* __restrict__ seg,
                                                 int* __restrict__ cnt, int* __restrict__ eidx)
{
    __shared__ int sh[128];
    __shared__ int S1s, C2s, tots;
    int t = threadIdx.x;
    int v = (t < NSB) ? bsum[t] : 0;
    sh[t] = v;
    __syncthreads();
    for (int off = 1; off < 128; off <<= 1) {
        int add = (t >= off) ? sh[t - off] : 0;
        __syncthreads();
        sh[t] += add;
        __syncthreads();
    }
    int pre = sh[t] - v;      // exclusive prefix over block sums
    if (t == 31) S1s = sh[31];
    if (t == 63) C2s = sh[63];
    if (t == NSB - 1) tots = sh[NSB - 1];
    __syncthreads();
    int S1 = S1s, C2 = C2s, tot = tots;
    int pad1 = (16 - (S1 & 15)) & 15;
    int pad2 = (16 - ((C2 + pad1) & 15)) & 15;
    if (t < NSB) {
        int add = ((t >= 32) ? pad1 : 0) + ((t >= 64) ? pad2 : 0);
        bsum[t] = pre + add;
    }
    if (t == NSB) bsum[NSB] = 0;   // zgout reads bsum[96] for the final bucket bound
    // fill ONLY the pad/tail slots of eidx with -1 (replaces 1.2 MB memset)
    if (t < 16) {
        if (t < pad1) eidx[S1 + t] = -1;
    } else if (t < 32) {
        int i = t - 16;
        if (i < pad2) eidx[C2 + pad1 + i] = -1;
    } else if (t < 48) {
        int i = t - 32;
        int T = tot + pad1 + pad2;
        int Tr = (T + 15) & ~15;
        if (T + i < Tr) eidx[T + i] = -1;
    }
    if (t == 0) {
        seg[0] = 0;
        seg[1] = S1 + pad1;
        seg[2] = C2 + pad1 + pad2;
        seg[3] = tot + pad1 + pad2;
        cnt[NKEY] = tot + pad1 + pad2;
    }
}

__global__ __launch_bounds__(256) void scatter_kernel(
    const int* __restrict__ receivers, const int* __restrict__ e_type,
    const int* __restrict__ cnt, const int* __restrict__ bsum,
    const int* __restrict__ rank, int* __restrict__ eidx)
{
    int e = blockIdx.x * 256 + threadIdx.x;
    if (e >= NE) return;
    int rk = rank[e];
    if (rk < 0) return;
    int r = receivers[e];
    int bb = r / N_PART;
    int p = r - bb * N_PART;
    int et = e_type[e];
    int t = (et == 1) ? 0 : ((et == 3) ? 1 : 2);
    int key = t * N_ESLOT + (bb * N_ELEC + p - N_NUC);
    eidx[cnt[key] + bsum[key >> 10] + rk] = e;
}

// ================= fused edge kernel: software-pipelined grid-stride =================
__global__ __launch_bounds__(256, 4) void edge_fused(
    const float* __restrict__ dist, const int* __restrict__ senders,
    const int* __restrict__ eidx, const int* __restrict__ seg,
    const bf16x8* __restrict__ W1p, const float* __restrict__ b1cat,
    const bf16x8* __restrict__ W2p, const float* __restrict__ b2cat,
    const ushort_t* __restrict__ hxb, ushort_t* __restrict__ buf)
{
    __shared__ ushort_t tr[4][16 * TRS];
    int tid = threadIdx.x;
    int wave = tid >> 6, lane = tid & 63;
    int l15 = lane & 15, l4 = lane >> 4;
    int total = seg[3], s1 = seg[1], s2 = seg[2];
    ushort_t* trw = tr[wave];
    int nw = gridDim.x * 4;

    int tile = blockIdx.x * 4 + wave;
    if (tile * 16 >= total) return;

    // prologue: prefetch tile 0 inputs
    int e = eidx[tile * 16 + l15];
    int valid = (e >= 0) ? 1 : 0;
    int ec = valid ? e : 0;
    int snd = senders[ec];
    const float* dp = dist + (size_t)ec * DD + l4 * 8;
    f32x4 v0 = __builtin_nontemporal_load((const f32x4*)(dp));
    f32x4 v1 = __builtin_nontemporal_load((const f32x4*)(dp + 4));
    f32x4 v2 = __builtin_nontemporal_load((const f32x4*)(dp + 32));
    f32x4 v3 = __builtin_nontemporal_load((const f32x4*)(dp + 36));

    while (true) {
        // (1) issue hx[sender] gathers for the CURRENT tile up front — they cover the MFMA chain
        bf16x8 hv[4];
        int vr[4];
#pragma unroll
        for (int r = 0; r < 4; ++r) {
            int m = l4 * 4 + r;
            int sdr = __shfl(snd, m);
            vr[r] = __shfl(valid, m);
            hv[r] = *(const bf16x8*)(hxb + (size_t)sdr * KK + l15 * 8);
        }

        // (2) convert current A-frags (frees v0..v3 for the next prefetch)
        union { bf16x8 v; unsigned int u[4]; } A0, A1;
        A0.u[0] = cvtpk(v0[0], v0[1]); A0.u[1] = cvtpk(v0[2], v0[3]);
        A0.u[2] = cvtpk(v1[0], v1[1]); A0.u[3] = cvtpk(v1[2], v1[3]);
        A1.u[0] = cvtpk(v2[0], v2[1]); A1.u[1] = cvtpk(v2[2], v2[3]);
        A1.u[2] = cvtpk(v3[0], v3[1]); A1.u[3] = cvtpk(v3[2], v3[3]);

        // (3) prefetch NEXT tile's inputs — latency hides under MFMAs below
        int ntile = tile + nw;
        int more = (ntile * 16 < total) ? 1 : 0;
        int valid_n = 0, snd_n = 0;
        if (more) {
            int e_n = eidx[ntile * 16 + l15];
            valid_n = (e_n >= 0) ? 1 : 0;
            int ecn = valid_n ? e_n : 0;
            snd_n = senders[ecn];
            const float* dpn = dist + (size_t)ecn * DD + l4 * 8;
            v0 = __builtin_nontemporal_load((const f32x4*)(dpn));
            v1 = __builtin_nontemporal_load((const f32x4*)(dpn + 4));
            v2 = __builtin_nontemporal_load((const f32x4*)(dpn + 32));
            v3 = __builtin_nontemporal_load((const f32x4*)(dpn + 36));
        }

        int t = (tile * 16 >= s1) + (tile * 16 >= s2);

        // (4) h1 = ssp(dist @ W1[t] + b1[t])  (8 MFMA, bias in acc)
        f32x4 ah[4];
#pragma unroll
        for (int q = 0; q < 4; ++q) ah[q] = (f32x4)(b1cat[t * 64 + q * 16 + l15]);
        const bf16x8* W1b = W1p + (size_t)(t * 4) * 2 * 64;
#pragma unroll
        for (int q = 0; q < 4; ++q) {
            bf16x8 b0 = W1b[(q * 2 + 0) * 64 + lane];
            bf16x8 b1v = W1b[(q * 2 + 1) * 64 + lane];
            ah[q] = __builtin_amdgcn_mfma_f32_16x16x32_bf16(A0.v, b0, ah[q], 0, 0, 0);
            ah[q] = __builtin_amdgcn_mfma_f32_16x16x32_bf16(A1.v, b1v, ah[q], 0, 0, 0);
        }

        // ssp + per-wave LDS transpose (C-frag -> A-frag)
#pragma unroll
        for (int q = 0; q < 4; ++q) {
#pragma unroll
            for (int r = 0; r < 4; ++r) {
                trw[(l4 * 4 + r) * TRS + q * 16 + l15] = f2b_hup(ssp_fast(ah[q][r]));
            }
        }
        bf16x8 a2_0 = *(const bf16x8*)&trw[l15 * TRS + l4 * 8];
        bf16x8 a2_1 = *(const bf16x8*)&trw[l15 * TRS + 32 + l4 * 8];

        // (5) weh = h1 @ W2[t] + b2[t]  (16 MFMA, bias in acc)
        f32x4 aw[8];
#pragma unroll
        for (int n = 0; n < 8; ++n) aw[n] = (f32x4)(b2cat[t * KK + n * 16 + l15]);
        const bf16x8* W2b = W2p + (size_t)(t * 8) * 2 * 64;
#pragma unroll
        for (int n = 0; n < 8; ++n) {
            bf16x8 b0 = W2b[(n * 2 + 0) * 64 + lane];
            bf16x8 b1v = W2b[(n * 2 + 1) * 64 + lane];
            aw[n] = __builtin_amdgcn_mfma_f32_16x16x32_bf16(a2_0, b0, aw[n], 0, 0, 0);
            aw[n] = __builtin_amdgcn_mfma_f32_16x16x32_bf16(a2_1, b1v, aw[n], 0, 0, 0);
        }

        // (6) epilogue: * hx (already in regs), packed cvt, cached store (zgout reads it from L3)
#pragma unroll
        for (int r = 0; r < 4; ++r) {
            float p0 = aw[0][r] * b2f((unsigned short)hv[r][0]);
            float p1 = aw[1][r] * b2f((unsigned short)hv[r][1]);
            float p2 = aw[2][r] * b2f((unsigned short)hv[r][2]);
            float p3 = aw[3][r] * b2f((unsigned short)hv[r][3]);
            float p4 = aw[4][r] * b2f((unsigned short)hv[r][4]);
            float p5 = aw[5][r] * b2f((unsigned short)hv[r][5]);
            float p6 = aw[6][r] * b2f((unsigned short)hv[r][6]);
            float p7 = aw[7][r] * b2f((unsigned short)hv[r][7]);
            union { bf16x8 v; unsigned int u[4]; } O;
            O.u[0] = vr[r] ? cvtpk(p0, p1) : 0u;
            O.u[1] = vr[r] ? cvtpk(p2, p3) : 0u;
            O.u[2] = vr[r] ? cvtpk(p4, p5) : 0u;
            O.u[3] = vr[r] ? cvtpk(p6, p7) : 0u;
            *(bf16x8*)(buf + (size_t)(tile * 16 + l4 * 4 + r) * KK + l15 * 8) = O.v;
        }

        if (!more) break;
        tile = ntile;
        valid = valid_n;
        snd = snd_n;
    }
}

// ================= zgout: fused zgather (→LDS) + gout MFMA, 32 slots/block =================
__global__ __launch_bounds__(512, 4) void zgout_fused(
    const int* __restrict__ cnt, const int* __restrict__ bsum,
    const ushort_t* __restrict__ buf,
    const float* __restrict__ elec, const ushort_t* __restrict__ GT,
    const float* __restrict__ gbsum, float* __restrict__ out)
{
    __shared__ ushort_t zl[32 * ZLS];   // 25,088 B
    __shared__ int bnd[3][33];
    int tid = threadIdx.x;
    int lane = tid & 63;
    int wave = tid >> 6;
    int l15 = lane & 15, l4 = lane >> 4;
    int s0 = blockIdx.x * 32;

    // ---- bounds preload (96 buckets + 3 segment ends) ----
    if (tid < 99) {
        int tt = tid / 33;
        int sl = tid - tt * 33;
        int idx = tt * N_ESLOT + s0 + sl;
        bnd[tt][sl] = cnt[idx] + bsum[idx >> 10];
    }
    __syncthreads();

    // ---- phase 1: bucket sums -> LDS (2 rows per uint2 load) ----
    for (int b = wave; b < 96; b += 8) {
        int sl = b & 31;
        int t  = b >> 5;
        int lo = bnd[t][sl];
        int hi = bnd[t][sl + 1];
        float a0 = 0.0f, a1 = 0.0f, a2 = 0.0f, a3 = 0.0f;
        int i = lo;
        for (; i + 2 <= hi; i += 2) {
            // lanes 0..31 read row i, lanes 32..63 read row i+1 (512B total)
            uint2 v = *(const uint2*)(buf + (size_t)i * KK + 4 * lane);
            a0 += b2f((unsigned short)(v.x & 0xffff));
            a1 += b2f((unsigned short)(v.x >> 16));
            a2 += b2f((unsigned short)(v.y & 0xffff));
            a3 += b2f((unsigned short)(v.y >> 16));
        }
        if (i < hi) {
            uint2 v; v.x = 0u; v.y = 0u;
            if (lane < 32) v = *(const uint2*)(buf + (size_t)i * KK + 4 * lane);
            a0 += b2f((unsigned short)(v.x & 0xffff));
            a1 += b2f((unsigned short)(v.x >> 16));
            a2 += b2f((unsigned short)(v.y & 0xffff));
            a3 += b2f((unsigned short)(v.y >> 16));
        }
        // fold row-parity halves: lane l += lane l^32
        a0 += __shfl_xor(a0, 32);
        a1 += __shfl_xor(a1, 32);
        a2 += __shfl_xor(a2, 32);
        a3 += __shfl_xor(a3, 32);
        if (lane < 32) {
            int base = sl * ZLS + t * KK;
            int p = 4 * lane;
            zl[base + ((p    ) >> 3) + (((p    ) & 7) * 16)] = f2b_hup(a0);
            zl[base + ((p + 1) >> 3) + (((p + 1) & 7) * 16)] = f2b_hup(a1);
            zl[base + ((p + 2) >> 3) + (((p + 2) & 7) * 16)] = f2b_hup(a2);
            zl[base + ((p + 3) >> 3) + (((p + 3) & 7) * 16)] = f2b_hup(a3);
        }
    }
    __syncthreads();

    // ---- phase 2: out = elec + Z @ GT + gb (MFMA, swapped operands) ----
    // 8 waves = 2 row-waves x 4 col-quarters; wave does 16 rows x 64 cols (4 nt)
    int rw = wave & 1;
    int ch = wave >> 1;
    int row0 = s0 + rw * 16;
    int lrow = rw * 16 + l15;
    int ntb = ch * 4;

    bf16x8 zb[12];
#pragma unroll
    for (int ks = 0; ks < 12; ++ks)
        zb[ks] = *(const bf16x8*)&zl[lrow * ZLS + ks * 32 + l4 * 8];

    f32x4 acc[4];
#pragma unroll
    for (int nt = 0; nt < 4; ++nt) acc[nt] = (f32x4)(0.0f);
#pragma unroll
    for (int nt = 0; nt < 4; ++nt) {
#pragma unroll
        for (int ks = 0; ks < 12; ++ks) {
            bf16x8 g = *(const bf16x8*)(GT + ((size_t)((ntb + nt) * 12 + ks) * 64 + lane) * 8);
            acc[nt] = __builtin_amdgcn_mfma_f32_16x16x32_bf16(g, zb[ks], acc[nt], 0, 0, 0);
        }
    }

#pragma unroll
    for (int nt = 0; nt < 4; ++nt) {
        int n0 = (ntb + nt) * 16 + l4 * 4;
        f32x4 gbv = *(const f32x4*)(gbsum + n0);
        size_t o = (size_t)(row0 + l15) * EMB + n0;
        f32x4 ev = *(const f32x4*)(elec + o);
        f32x4 res;
        res[0] = ev[0] + acc[nt][0] + gbv[0];
        res[1] = ev[1] + acc[nt][1] + gbv[1];
        res[2] = ev[2] + acc[nt][2] + gbv[2];
        res[3] = ev[3] + acc[nt][3] + gbv[3];
        *(f32x4*)(out + o) = res;
    }
}

extern "C" void kernel_launch(void* const* d_in, const int* in_sizes, int n_in,
                              void* d_out, int out_size, void* d_ws, size_t ws_size,
                              hipStream_t stream) {
    const float* nuc       = (const float*)d_in[0];
    const float* elec      = (const float*)d_in[1];
    const float* dist      = (const float*)d_in[2];
    const int*   e_type    = (const int*)d_in[3];
    const int*   senders   = (const int*)d_in[4];
    const int*   receivers = (const int*)d_in[5];
    const float* w_same_W1 = (const float*)d_in[6];
    const float* w_same_b1 = (const float*)d_in[7];
    const float* w_same_W2 = (const float*)d_in[8];
    const float* w_same_b2 = (const float*)d_in[9];
    const float* w_anti_W1 = (const float*)d_in[10];
    const float* w_anti_b1 = (const float*)d_in[11];
    const float* w_anti_W2 = (const float*)d_in[12];
    const float* w_anti_b2 = (const float*)d_in[13];
    const float* w_n_W1    = (const float*)d_in[14];
    const float* w_n_b1    = (const float*)d_in[15];
    const float* w_n_W2    = (const float*)d_in[16];
    const float* w_n_b2    = (const float*)d_in[17];
    const float* h_W       = (const float*)d_in[18];
    const float* h_b       = (const float*)d_in[19];
    const float* g_same_W  = (const float*)d_in[20];
    const float* g_same_b  = (const float*)d_in[21];
    const float* g_anti_W  = (const float*)d_in[22];
    const float* g_anti_b  = (const float*)d_in[23];
    const float* g_n_W     = (const float*)d_in[24];
    const float* g_n_b     = (const float*)d_in[25];

    float* out = (float*)d_out;

    // ---- workspace layout ----
    char* w = (char*)d_ws;
    ushort_t* pack = (ushort_t*)w;                         // 20992*16 = 335,872 B
    size_t off = 20992 * 16;
    float* b1cat = (float*)(w + off);  off += 192 * 4;
    float* b2cat = (float*)(w + off);  off += 384 * 4;
    float* gbsum = (float*)(w + off);  off += 256 * 4;
    int*   seg   = (int*)(w + off);    off += 4 * 4;
    off = (off + 255) & ~(size_t)255;
    int*   bsum  = (int*)(w + off);    off += 128 * 4;
    off = (off + 255) & ~(size_t)255;
    ushort_t* hxb = (ushort_t*)(w + off);  off += (size_t)N_NODES * KK * 2;        // 10.5 MB
    ushort_t* buf = (ushort_t*)(w + off);  off += (size_t)(NE + 64) * KK * 2;      // 78.7 MB
    int* cnt  = (int*)(w + off);  off += (size_t)(NKEY + 1) * 4 + 252; off &= ~(size_t)255;
    int* rank = (int*)(w + off);  off += (size_t)NE * 4;
    int* eidx = (int*)(w + off);  off += (size_t)(NE + 64) * 4;

    const ushort_t* W1pack = pack;
    const ushort_t* W2pack = pack + (size_t)1536 * 8;
    const ushort_t* HWT    = pack + (size_t)(1536 + 3072) * 8;
    const ushort_t* GT     = pack + (size_t)(1536 + 3072 + 4096) * 8;

    // A: zero_cnt (96) | prep (86) | hx_nuc (512)  = 694 blocks
    setup_kernel<<<694, 256, 0, stream>>>(
        nuc,
        w_n_W1, w_same_W1, w_anti_W1, w_n_W2, w_same_W2, w_anti_W2,
        h_W, g_n_W, g_same_W, g_anti_W,
        w_n_b1, w_same_b1, w_anti_b1, w_n_b2, w_same_b2, w_anti_b2,
        g_n_b, g_same_b, g_anti_b,
        (ushort_t*)pack, b1cat, b2cat, gbsum, cnt, hxb);

    // B: hx_elec (512) | hist (1200) = 1712 blocks
    build_kernel<<<1712, 256, 0, stream>>>(
        elec, HWT, h_b, hxb, receivers, e_type, cnt, rank);

    scan_local<<<NSB, 256, 0, stream>>>(cnt, bsum);
    scan_bsum<<<1, 128, 0, stream>>>(bsum, seg, cnt, eidx);
    scatter_kernel<<<NE / 256, 256, 0, stream>>>(receivers, e_type, cnt, bsum, rank, eidx);

    edge_fused<<<2048, 256, 0, stream>>>(dist, senders, eidx, seg,
        (const bf16x8*)W1pack, b1cat, (const bf16x8*)W2pack, b2cat, hxb, buf);

    zgout_fused<<<N_ESLOT / 32, 512, 0, stream>>>(cnt, bsum, buf, elec, GT, gbsum, out);
}